// Round 11
// baseline (551.586 us; speedup 1.0000x reference)
//
#include <hip/hip_runtime.h>

// ---------------------------------------------------------------------------
// VQ-VAE forward. R19 = R18 + dispatch fusion + vq setprio A/B.
//  - merge_kernel + loss_kernel + fin_kernel fused into vq_post (4096 blocks):
//    per-row 8-seg merge in-wave (lexicographic (d,k) tree-min == sequential
//    scan), lane0 writes vidx/out_idx, all lanes do the loss contribution
//    (same per-row FP reduction order as before; cross-block atomic order was
//    already non-deterministic). Device-scope ticket -> last block writes the
//    loss outputs. 18 -> 16 dispatches.
//  - vq_mfma: s_setprio dropped (m190: ~0-to-negative in barrier-lockstep
//    structures; inherited untested from R9). Clean per-dispatch A/B.
//  - Conv fleet / prep / vq schedule otherwise R18-verbatim.
// ---------------------------------------------------------------------------

typedef _Float16 half8 __attribute__((ext_vector_type(8)));
typedef _Float16 half4v __attribute__((ext_vector_type(4)));
typedef float f32x4 __attribute__((ext_vector_type(4)));
typedef float f32x16 __attribute__((ext_vector_type(16)));

#define GL_LDS(src, dst) \
  __builtin_amdgcn_global_load_lds((const __attribute__((address_space(1))) void*)(src), \
                                   (__attribute__((address_space(3))) void*)(dst), 16, 0, 0)

struct CP2 {
  const _Float16* inH; const _Float16* inL;
  const _Float16* wH; const _Float16* wL;
  const float* bias; const _Float16* zpad;
  float* outF; _Float16* outH; _Float16* outL;
  const int* vidx;
  int Ci, lg2Ci, Ti, Co, To, K2, stride, pad, lg2U, Umask;
};

template<int SP, int PAR, bool GATHER, bool RELU, int OM>
__global__ __launch_bounds__(256, 4) void conv_mfma(CP2 p) {
  __shared__ _Float16 As[2][SP * 2048];
  __shared__ _Float16 Bs[2][SP * 2048];
  const int tid = threadIdx.x;
  const int w = tid >> 6;
  const int lane = tid & 63;
  const int m = lane & 15, q = lane >> 4;
  const int btbase = blockIdx.x * 64;
  const int cobase = blockIdx.y * 64;
  const int bt = btbase + w * 16 + m;          // this lane's row (stage & MFMA)
  const int b = bt >> p.lg2U, u = bt & p.Umask;
  const int nkb = p.K2 >> 5;
  const int lw = w * 512;                      // wave-uniform LDS offset (halfs)

  int er0 = 0, er1 = 0;                        // gather codes (dt = tap only)
  if (GATHER) {
    er0 = p.vidx[b * p.Ti + u];                // tin = u (tap 0)
    if (PAR == 1) er1 = (u + 1 < p.Ti) ? p.vidx[b * p.Ti + u + 1] : 0;
  }

  auto stage = [&](int kb, int buf) {
    const int k0 = kb << 5;
    const int tap = k0 >> p.lg2Ci;
    const int ci0 = k0 & (p.Ci - 1);
    int dt;
    if (PAR == 0)      dt = 0;
    else if (PAR == 1) dt = tap;
    else               dt = tap - p.pad;
    const int tin = (PAR < 0) ? u * p.stride + dt : u + dt;
    const bool ok = (tin >= 0) && (tin < p.Ti);
    int ai;
    if (GATHER) {
      const int er = (PAR == 1 && tap == 1) ? er1 : er0;
      ai = er * 256 + ci0 + q * 8;
    } else {
      ai = (b * p.Ti + tin) * p.Ci + ci0 + q * 8;
    }
    GL_LDS(ok ? &p.inH[ai] : p.zpad, &As[buf][lw]);
    if (SP == 2) GL_LDS(ok ? &p.inL[ai] : p.zpad, &As[buf][2048 + lw]);
    const int wb = (blockIdx.y * nkb + kb) * 2048 + lw + lane * 8;
    GL_LDS(&p.wH[wb], &Bs[buf][lw]);
    if (SP == 2) GL_LDS(&p.wL[wb], &Bs[buf][2048 + lw]);
  };

  f32x4 acc[4];
#pragma unroll
  for (int j = 0; j < 4; ++j) acc[j] = {0.f, 0.f, 0.f, 0.f};

  stage(0, 0);
  for (int kb = 0; kb < nkb; ++kb) {
    const int buf = kb & 1;
    __syncthreads();                           // drains stage(kb); WAR-safe
    if (kb + 1 < nkb) stage(kb + 1, buf ^ 1);  // in flight across MFMA
    const half8 a1 = *(const half8*)&As[buf][lw + lane * 8];
    half8 a2;
    if (SP == 2) a2 = *(const half8*)&As[buf][2048 + lw + lane * 8];
#pragma unroll
    for (int ct = 0; ct < 4; ++ct) {
      const half8 b1 = *(const half8*)&Bs[buf][ct * 512 + lane * 8];
      half8 b2;
      if (SP == 2) b2 = *(const half8*)&Bs[buf][2048 + ct * 512 + lane * 8];
      acc[ct] = __builtin_amdgcn_mfma_f32_16x16x32_f16(a1, b1, acc[ct], 0, 0, 0);
      if (SP == 2) {
        acc[ct] = __builtin_amdgcn_mfma_f32_16x16x32_f16(a2, b1, acc[ct], 0, 0, 0);
        acc[ct] = __builtin_amdgcn_mfma_f32_16x16x32_f16(a1, b2, acc[ct], 0, 0, 0);
      }
    }
  }
#pragma unroll
  for (int ct = 0; ct < 4; ++ct) {
    const int co = cobase + ct * 16 + m;
    if (co < p.Co) {
      const float bv = p.bias[co];
#pragma unroll
      for (int j = 0; j < 4; ++j) {
        const int row = btbase + w * 16 + q * 4 + j;
        const int bb = row >> p.lg2U, uu = row & p.Umask;
        float v = acc[ct][j] + bv;
        if (RELU) v = fmaxf(v, 0.f);
        const int t = (PAR < 0) ? uu : 2 * uu + PAR;
        const int oi = (bb * p.To + t) * p.Co + co;
        if (OM == 3) {
          p.outF[oi] = v;
        } else if (OM == 1) {
          p.outH[oi] = (_Float16)v;
        } else {
          const _Float16 h = (_Float16)v;
          const _Float16 l = (_Float16)(v - (float)h);
          p.outH[oi] = h; p.outL[oi] = l;
        }
      }
    }
  }
}

struct CPD {
  const _Float16* inH; const _Float16* wS; const float* bias;
  const _Float16* zpad;
  float* outF; _Float16* outH;
  int Ci, Ti, Co, To, lg2U, Umask;
};

template<bool RELU, bool F32OUT>
__global__ __launch_bounds__(256, 4) void conv_dec(CPD p) {
  __shared__ _Float16 As[2][2560];             // rows 0-63 + rows 64-79 extra
  __shared__ _Float16 Bs[2][6144];             // 3 taps, fragment-linear
  const int tid = threadIdx.x;
  const int w = tid >> 6;
  const int lane = tid & 63;
  const int m = lane & 15, q = lane >> 4;
  const int btbase = blockIdx.x * 64;
  const int cobase = blockIdx.y * 64;
  const int b0 = btbase >> p.lg2U;
  const int u0 = btbase & p.Umask;
  const int nkb = p.Ci >> 5;
  const int lw = w * 512;

  auto stage = [&](int kb, int buf) {
    const int ci0 = kb << 5;
    {
      const int ur = u0 + w * 16 + m;
      const bool ok = ur < p.Ti;
      GL_LDS(ok ? &p.inH[(b0 * p.Ti + ur) * p.Ci + ci0 + q * 8] : p.zpad,
             &As[buf][lw]);
    }
    if (w == 0) {                              // rows 64-79 (only row 64 used)
      const int ur = u0 + 64 + m;
      const bool ok = ur < p.Ti;
      GL_LDS(ok ? &p.inH[(b0 * p.Ti + ur) * p.Ci + ci0 + q * 8] : p.zpad,
             &As[buf][2048]);
    }
    const int wb = (blockIdx.y * nkb + kb) * 6144;
#pragma unroll
    for (int tap = 0; tap < 3; ++tap)
      GL_LDS(&p.wS[wb + tap * 2048 + lw + lane * 8], &Bs[buf][tap * 2048 + lw]);
  };

  f32x4 aE[4], aO[4];
#pragma unroll
  for (int j = 0; j < 4; ++j) { aE[j] = {0.f,0.f,0.f,0.f}; aO[j] = {0.f,0.f,0.f,0.f}; }

  stage(0, 0);
  for (int kb = 0; kb < nkb; ++kb) {
    const int buf = kb & 1;
    __syncthreads();
    if (kb + 1 < nkb) stage(kb + 1, buf ^ 1);
    const int row = w * 16 + m;
    const half8 a0 = *(const half8*)&As[buf][lw + lane * 8];
    const int r1 = row + 1;
    const int s1 = (r1 >> 4) * 512 + ((r1 & 15) + (q << 4)) * 8;
    const half8 a1s = *(const half8*)&As[buf][s1];
#pragma unroll
    for (int ct = 0; ct < 4; ++ct) {
      const half8 w0 = *(const half8*)&Bs[buf][ct * 512 + lane * 8];
      const half8 w1 = *(const half8*)&Bs[buf][2048 + ct * 512 + lane * 8];
      const half8 w2 = *(const half8*)&Bs[buf][4096 + ct * 512 + lane * 8];
      aE[ct] = __builtin_amdgcn_mfma_f32_16x16x32_f16(a0,  w1, aE[ct], 0, 0, 0);
      aO[ct] = __builtin_amdgcn_mfma_f32_16x16x32_f16(a0,  w0, aO[ct], 0, 0, 0);
      aO[ct] = __builtin_amdgcn_mfma_f32_16x16x32_f16(a1s, w2, aO[ct], 0, 0, 0);
    }
  }
#pragma unroll
  for (int ct = 0; ct < 4; ++ct) {
    const int co = cobase + ct * 16 + m;
    if (co < p.Co) {
      const float bv = p.bias[co];
#pragma unroll
      for (int j = 0; j < 4; ++j) {
        const int u = u0 + w * 16 + q * 4 + j;
        float vE = aE[ct][j] + bv;
        float vO = aO[ct][j] + bv;
        if (RELU) { vE = fmaxf(vE, 0.f); vO = fmaxf(vO, 0.f); }
        const int oiE = (b0 * p.To + 2 * u) * p.Co + co;
        const int oiO = oiE + p.Co;
        if (F32OUT) { p.outF[oiE] = vE; p.outF[oiO] = vO; }
        else        { p.outH[oiE] = (_Float16)vE; p.outH[oiO] = (_Float16)vO; }
      }
    }
  }
}

// ---- prep kernels -----------------------------------------------------------

__global__ __launch_bounds__(256) void x_prep(const float* __restrict__ x,
                                              _Float16* __restrict__ h,
                                              _Float16* __restrict__ l,
                                              _Float16* __restrict__ zp,
                                              float* __restrict__ lacc,
                                              int* __restrict__ ticket) {
  if (blockIdx.x == 0) {
    if (threadIdx.x < 64) {                    // zero page for OOB staging
      const uint4 z = {0u, 0u, 0u, 0u};
      ((uint4*)zp)[threadIdx.x] = z;
    }
    if (threadIdx.x == 0) { *lacc = 0.f; *ticket = 0; }
  }
  const int i = blockIdx.x * 256 + threadIdx.x;   // 1,048,576 float4s
  const float4 v = ((const float4*)x)[i];
  half4v a, b;
  a.x = (_Float16)v.x; b.x = (_Float16)(v.x - (float)a.x);
  a.y = (_Float16)v.y; b.y = (_Float16)(v.y - (float)a.y);
  a.z = (_Float16)v.z; b.z = (_Float16)(v.z - (float)a.z);
  a.w = (_Float16)v.w; b.w = (_Float16)(v.w - (float)a.w);
  ((half4v*)h)[i] = a;
  ((half4v*)l)[i] = b;
}

struct WPE { const float* w; int dh, dl, Ci, lg2Ci, KWO, Co, PAR, SP, nkb, base, dec; };
struct WPA { WPE e[9]; };

// one block per (conv, coblk, kb) tile: writes staged f16 tile(s) in
// FRAGMENT-LINEAR order: slot = (cc>>4)*512 + ((cc&15) + (g<<4))*8.
__global__ __launch_bounds__(256) void w_prep(WPA a, _Float16* __restrict__ wst) {
  const int b = (int)blockIdx.x;
  int i = 0;
#pragma unroll
  for (int j = 1; j < 9; ++j) if (b >= a.e[j].base) i = j;
  const WPE E = a.e[i];
  const int local = b - E.base;
  const int cb = local / E.nkb;
  const int kb = local - cb * E.nkb;
  const int tid = threadIdx.x;
  const int cc = tid >> 2, g = tid & 3;
  const int co = cb * 64 + cc;
  const bool okc = co < E.Co;
  const int k0 = kb << 5;
  const int tap0 = k0 >> E.lg2Ci;
  const int ci0 = k0 & (E.Ci - 1);
  const int slot = (cc >> 4) * 512 + ((cc & 15) + (g << 4)) * 8;
  if (!E.dec) {
    const int ko = (E.PAR == 0) ? 1 : (E.PAR == 1 ? 2 * tap0 : tap0);
    half8 hv, lv;
#pragma unroll
    for (int j = 0; j < 8; ++j) {
      const float wv = okc ? E.w[(co * E.Ci + ci0 + g * 8 + j) * E.KWO + ko] : 0.f;
      hv[j] = (_Float16)wv;
      lv[j] = (_Float16)(wv - (float)hv[j]);
    }
    const int off = (cb * E.nkb + kb) * 2048 + slot;
    *(half8*)&wst[E.dh + off] = hv;
    if (E.SP == 2) *(half8*)&wst[E.dl + off] = lv;
  } else {
#pragma unroll
    for (int tap = 0; tap < 3; ++tap) {
      half8 hv;
#pragma unroll
      for (int j = 0; j < 8; ++j) {
        const float wv = okc ? E.w[(co * E.Ci + ci0 + g * 8 + j) * 3 + tap] : 0.f;
        hv[j] = (_Float16)wv;
      }
      *(half8*)&wst[E.dh + ((cb * E.nkb + kb) * 3 + tap) * 2048 + slot] = hv;
    }
  }
}

__global__ __launch_bounds__(256) void emb_prep(const float* __restrict__ emb,
                                                _Float16* __restrict__ hi,
                                                _Float16* __restrict__ lo,
                                                float* __restrict__ nrm) {
  const int k = blockIdx.x * 4 + (threadIdx.x >> 6);
  const int lane = threadIdx.x & 63;
  const int i = k * 64 + lane;
  const float4 v = ((const float4*)emb)[i];
  half4v a, b;
  a.x = (_Float16)v.x; b.x = (_Float16)(v.x - (float)a.x);
  a.y = (_Float16)v.y; b.y = (_Float16)(v.y - (float)a.y);
  a.z = (_Float16)v.z; b.z = (_Float16)(v.z - (float)a.z);
  a.w = (_Float16)v.w; b.w = (_Float16)(v.w - (float)a.w);
  ((half4v*)hi)[i] = a;
  ((half4v*)lo)[i] = b;
  double s = (double)v.x * v.x + (double)v.y * v.y +
             (double)v.z * v.z + (double)v.w * v.w;
  for (int off = 32; off; off >>= 1) s += __shfl_down(s, off);
  if (lane == 0) nrm[k] = (float)s;
}

// VQ argmin, R14 schedule; s_setprio removed (A/B vs 5 rounds of ~207-213us).
__global__ __launch_bounds__(256, 2) void vq_mfma(const _Float16* __restrict__ z1g,
                                                  const _Float16* __restrict__ z2g,
                                                  const _Float16* __restrict__ e1g,
                                                  const _Float16* __restrict__ e2g,
                                                  const float* __restrict__ nrm,
                                                  float* __restrict__ pbest,
                                                  int* __restrict__ pidx) {
  __shared__ _Float16 es[2 * 2 * 4096];   // [buf][arr][4096 halfs] = 32 KB
  const int tid = threadIdx.x;
  const int lane = tid & 63;
  const int w = tid >> 6;
  const int m32 = lane & 31;
  const int hi = lane >> 5;
  const int seg = blockIdx.x & 7, rb = blockIdx.x >> 3;   // XCD = bid%8 = seg
  const int rbase = rb * 128;
  const int row_g = rbase + w * 32 + m32;

  half8 za[16], zb[16];
#pragma unroll
  for (int c = 0; c < 16; ++c) {
    const int zi = row_g * 256 + c * 16 + hi * 8;
    za[c] = *(const half8*)&z1g[zi];
    zb[c] = *(const half8*)&z2g[zi];
  }

  float best[16]; int bk[16];
#pragma unroll
  for (int i = 0; i < 16; ++i) { best[i] = 3.4e38f; bk[i] = 0; }

  const int sbase = (seg * 1024 + ((tid >> 7) & 1) * 32 + (tid & 31)) * 256
                  + ((tid >> 6) & 1) * 16 + ((tid >> 5) & 1) * 8;
  const int lw = w * 512;                 // wave-uniform LDS dst (halfs)

  auto stage = [&](int cc_, int kb_, int buf_) {
    const int off = sbase + cc_ * 32768 + kb_ * 32;
    __builtin_amdgcn_global_load_lds(
        (const __attribute__((address_space(1))) void*)(e1g + off),
        (__attribute__((address_space(3))) void*)&es[(buf_ * 2 + 0) * 4096 + lw], 16, 0, 0);
    __builtin_amdgcn_global_load_lds(
        (const __attribute__((address_space(1))) void*)(e1g + off + 16384),
        (__attribute__((address_space(3))) void*)&es[(buf_ * 2 + 0) * 4096 + 2048 + lw], 16, 0, 0);
    __builtin_amdgcn_global_load_lds(
        (const __attribute__((address_space(1))) void*)(e2g + off),
        (__attribute__((address_space(3))) void*)&es[(buf_ * 2 + 1) * 4096 + lw], 16, 0, 0);
    __builtin_amdgcn_global_load_lds(
        (const __attribute__((address_space(1))) void*)(e2g + off + 16384),
        (__attribute__((address_space(3))) void*)&es[(buf_ * 2 + 1) * 4096 + 2048 + lw], 16, 0, 0);
  };

  stage(0, 0, 0);                         // prologue: step (cc=0,kb=0) -> buf0

  const int lb = lane * 8;                // read base (halfs)
  f32x16 acc[4];
  for (int cc = 0; cc < 8; ++cc) {
    const int cbase = seg * 1024 + cc * 128;
#pragma unroll
    for (int ct = 0; ct < 4; ++ct) {
#pragma unroll
      for (int rg = 0; rg < 16; ++rg) acc[ct][rg] = 0.f;
    }
#pragma unroll
    for (int kb = 0; kb < 8; ++kb) {
      const int buf = kb & 1;
      const _Float16* e1s = &es[(buf * 2 + 0) * 4096];
      const _Float16* e2s = &es[(buf * 2 + 1) * 4096];
      __syncthreads();
      if (kb < 7)      stage(cc, kb + 1, buf ^ 1);
      else if (cc < 7) stage(cc + 1, 0, buf ^ 1);
#pragma unroll
      for (int ct = 0; ct < 4; ++ct) {
#pragma unroll
        for (int k16 = 0; k16 < 2; ++k16) {
          const half8 b1 = *(const half8*)&e1s[ct * 1024 + k16 * 512 + lb];
          const half8 b2 = *(const half8*)&e2s[ct * 1024 + k16 * 512 + lb];
          const half8 a1 = za[kb * 2 + k16];
          const half8 a2 = zb[kb * 2 + k16];
          acc[ct] = __builtin_amdgcn_mfma_f32_32x32x16_f16(a1, b1, acc[ct], 0, 0, 0);
          acc[ct] = __builtin_amdgcn_mfma_f32_32x32x16_f16(a2, b1, acc[ct], 0, 0, 0);
          acc[ct] = __builtin_amdgcn_mfma_f32_32x32x16_f16(a1, b2, acc[ct], 0, 0, 0);
        }
      }
    }
#pragma unroll
    for (int ct = 0; ct < 4; ++ct) {
      const int k = cbase + ct * 32 + m32;
      const float nv = nrm[k];
#pragma unroll
      for (int rg = 0; rg < 16; ++rg) {
        const float d = nv - 2.f * acc[ct][rg];
        if (d < best[rg]) { best[rg] = d; bk[rg] = k; }
      }
    }
  }
#pragma unroll
  for (int rg = 0; rg < 16; ++rg) {
    float bv = best[rg]; int kv = bk[rg];
    for (int off = 1; off < 32; off <<= 1) {
      const float ob = __shfl_xor(bv, off);
      const int ok = __shfl_xor(kv, off);
      if (ob < bv || (ob == bv && ok < kv)) { bv = ob; kv = ok; }
    }
    if (m32 == 0) {
      const int row = rbase + w * 32 + (rg & 3) + 8 * (rg >> 2) + 4 * hi;
      pbest[seg * 16384 + row] = bv;
      pidx[seg * 16384 + row] = kv;
    }
  }
}

// Fused merge + loss + fin. One wave per row: lanes 0-7 merge the 8 segment
// candidates (lexicographic (d,k) min == sequential scan), lane0 writes
// vidx/out_idx, all 64 lanes compute the loss contribution (4 ch each, same
// per-row FP order as the old loss_kernel). Last block (device-scope ticket)
// writes the final loss outputs.
__global__ __launch_bounds__(256) void vq_post(const _Float16* __restrict__ z1g,
                                               const _Float16* __restrict__ z2g,
                                               const float* __restrict__ emb,
                                               const float* __restrict__ pbest,
                                               const int* __restrict__ pidx,
                                               int* __restrict__ vidx,
                                               float* __restrict__ out_idx,
                                               float* __restrict__ lacc,
                                               int* __restrict__ ticket,
                                               float* __restrict__ out, int loff) {
  const int wv = threadIdx.x >> 6;
  const int lane = threadIdx.x & 63;
  const int n = blockIdx.x * 4 + wv;          // row
  float bv = 3.4e38f; int kv = 0x7fffffff;
  if (lane < 8) { bv = pbest[lane * 16384 + n]; kv = pidx[lane * 16384 + n]; }
  for (int off = 4; off; off >>= 1) {
    const float ob = __shfl_down(bv, off);
    const int ok = __shfl_down(kv, off);
    if (ob < bv || (ob == bv && ok < kv)) { bv = ob; kv = ok; }
  }
  kv = __shfl(kv, 0);
  if (lane == 0) { vidx[n] = kv; out_idx[n] = (float)kv; }
  const int c = lane * 4;
  const half4v a = *(const half4v*)&z1g[n * 256 + c];
  const half4v b = *(const half4v*)&z2g[n * 256 + c];
  const float4 q4 = *(const float4*)&emb[kv * 256 + c];
  const float dx = ((float)a.x + (float)b.x) - q4.x;
  const float dy = ((float)a.y + (float)b.y) - q4.y;
  const float dz = ((float)a.z + (float)b.z) - q4.z;
  const float dw = ((float)a.w + (float)b.w) - q4.w;
  float s = dx * dx + dy * dy + dz * dz + dw * dw;
  for (int off = 32; off; off >>= 1) s += __shfl_down(s, off);
  __shared__ float red[4];
  if (lane == 0) red[wv] = s;
  __syncthreads();
  if (threadIdx.x == 0) {
    atomicAdd(lacc, red[0] + red[1] + red[2] + red[3]);
    __threadfence();
    if (atomicAdd(ticket, 1) == (int)gridDim.x - 1) {
      const float l = atomicAdd(lacc, 0.f) * (1.f / 4194304.f);
      out[loff] = l;
      out[loff + 1] = l;
    }
  }
}

extern "C" void kernel_launch(void* const* d_in, const int* in_sizes, int n_in,
                              void* d_out, int out_size, void* d_ws, size_t ws_size,
                              hipStream_t stream) {
  const float* x   = (const float*)d_in[0];
  const float* ew0 = (const float*)d_in[1];  const float* eb0 = (const float*)d_in[2];
  const float* ew1 = (const float*)d_in[3];  const float* eb1 = (const float*)d_in[4];
  const float* ew2 = (const float*)d_in[5];  const float* eb2 = (const float*)d_in[6];
  const float* pw  = (const float*)d_in[7];  const float* pb  = (const float*)d_in[8];
  const float* emb = (const float*)d_in[9];
  const float* dw0 = (const float*)d_in[10]; const float* db0 = (const float*)d_in[11];
  const float* dw1 = (const float*)d_in[12]; const float* db1 = (const float*)d_in[13];
  const float* dw2 = (const float*)d_in[14]; const float* db2 = (const float*)d_in[15];
  const float* dw3 = (const float*)d_in[16]; const float* db3 = (const float*)d_in[17];
  float* ws  = (float*)d_ws;
  float* out = (float*)d_out;

  const int A0 = 0, B0 = 4194304, C0 = 8388608, TL = 12582912;
  _Float16* h0h = (_Float16*)(ws + C0);            // x split (enc0 input)
  _Float16* h0l = h0h + 4194304;
  _Float16* h1h = (_Float16*)(ws + B0);
  _Float16* h1l = h1h + 4194304;
  _Float16* h2h = (_Float16*)(ws + A0);
  _Float16* h2l = h2h + 4194304;
  _Float16* h3h = (_Float16*)(ws + B0);
  _Float16* h3l = h3h + 4194304;
  _Float16* z1g = (_Float16*)(ws + A0);
  _Float16* z2g = z1g + 4194304;
  _Float16* e1g = (_Float16*)(ws + B0);
  _Float16* e2g = e1g + 2097152;
  float* pbest = ws + B0 + 2097152;
  int*   pidx  = (int*)(ws + B0 + 2097152 + 131072);
  _Float16* d1h = (_Float16*)(ws + C0);
  _Float16* d2h = (_Float16*)(ws + A0);
  _Float16* d3h = (_Float16*)(ws + B0);
  float* nrm  = ws + TL;
  int*   vidx = (int*)(ws + TL + 8192);
  float* lacc = ws + TL + 8192 + 16384;
  int*   ticket = (int*)(ws + TL + 8192 + 16384 + 1);
  _Float16* zpad = (_Float16*)(ws + TL + 26624);   // 1KB zero page
  _Float16* wst = (_Float16*)(ws + TL + 32768);    // staged weights (~1.44MB)

  // staged-weight offsets (halfs)
  const int W_E0H = 0,      W_E0L = 6144;
  const int W_E1H = 12288,  W_E1L = 36864;
  const int W_E2H = 61440,  W_E2L = 159744;
  const int W_PJH = 258048, W_PJL = 323584;
  const int W_D0A = 389120, W_D0B = 454656;
  const int W_DC1 = 585728, W_DC2 = 684032, W_DC3 = 708608;

  const int idx_off  = out_size - 16384;
  const int loss_off = out_size - 16386;

  // ---- prep: x split + zero page + lacc/ticket + weights (2 dispatches) ----
  x_prep<<<4096, 256, 0, stream>>>(x, h0h, h0l, zpad, lacc, ticket);
  WPA wa;
  wa.e[0] = {ew0, W_E0H, W_E0L, 32,  5, 3, 64,  -1, 2, 3,  0,   0};
  wa.e[1] = {ew1, W_E1H, W_E1L, 64,  6, 3, 128, -1, 2, 6,  3,   0};
  wa.e[2] = {ew2, W_E2H, W_E2L, 128, 7, 3, 256, -1, 2, 12, 15,  0};
  wa.e[3] = {pw,  W_PJH, W_PJL, 256, 8, 1, 256, -1, 2, 8,  63,  0};
  wa.e[4] = {dw0, W_D0A, 0,     256, 8, 3, 256,  0, 1, 8,  95,  0};
  wa.e[5] = {dw0, W_D0B, 0,     256, 8, 3, 256,  1, 1, 16, 127, 0};
  wa.e[6] = {dw1, W_DC1, 0,     256, 8, 3, 128, -1, 1, 8,  191, 1};
  wa.e[7] = {dw2, W_DC2, 0,     128, 7, 3, 64,  -1, 1, 4,  207, 1};
  wa.e[8] = {dw3, W_DC3, 0,     64,  6, 3, 32,  -1, 1, 2,  211, 1};
  w_prep<<<213, 256, 0, stream>>>(wa, wst);

  CP2 p; p.vidx = nullptr; p.inH = nullptr; p.inL = nullptr;
  p.outF = nullptr; p.outH = nullptr; p.outL = nullptr; p.zpad = zpad;

  // ---- encoder (3-pass f16 split MFMA; DMA staging; 64-row tiles) ----
  p.inH = h0h; p.inL = h0l; p.wH = wst + W_E0H; p.wL = wst + W_E0L;
  p.bias = eb0; p.outH = h1h; p.outL = h1l;
  p.Ci = 32; p.lg2Ci = 5; p.Ti = 512; p.Co = 64; p.To = 256;
  p.K2 = 96; p.stride = 2; p.pad = 1; p.lg2U = 8; p.Umask = 255;
  conv_mfma<2, -1, false, true, 0><<<dim3(1024, 1), 256, 0, stream>>>(p);

  p.inH = h1h; p.inL = h1l; p.wH = wst + W_E1H; p.wL = wst + W_E1L;
  p.bias = eb1; p.outH = h2h; p.outL = h2l;
  p.Ci = 64; p.lg2Ci = 6; p.Ti = 256; p.Co = 128; p.To = 128; p.K2 = 192;
  p.lg2U = 7; p.Umask = 127;
  conv_mfma<2, -1, false, true, 0><<<dim3(512, 2), 256, 0, stream>>>(p);

  p.inH = h2h; p.inL = h2l; p.wH = wst + W_E2H; p.wL = wst + W_E2L;
  p.bias = eb2; p.outH = h3h; p.outL = h3l;
  p.Ci = 128; p.lg2Ci = 7; p.Ti = 128; p.Co = 256; p.To = 64; p.K2 = 384;
  p.lg2U = 6; p.Umask = 63;
  conv_mfma<2, -1, false, true, 0><<<dim3(256, 4), 256, 0, stream>>>(p);

  p.inH = h3h; p.inL = h3l; p.wH = wst + W_PJH; p.wL = wst + W_PJL;
  p.bias = pb; p.outH = z1g; p.outL = z2g;
  p.Ci = 256; p.lg2Ci = 8; p.Ti = 64; p.Co = 256; p.To = 64;
  p.K2 = 256; p.stride = 1; p.pad = 0; p.lg2U = 6; p.Umask = 63;
  conv_mfma<2, -1, false, false, 0><<<dim3(256, 4), 256, 0, stream>>>(p);

  // ---- VQ ----
  emb_prep<<<2048, 256, 0, stream>>>(emb, e1g, e2g, nrm);
  vq_mfma<<<1024, 256, 0, stream>>>(z1g, z2g, e1g, e2g, nrm, pbest, pidx);
  vq_post<<<4096, 256, 0, stream>>>(z1g, z2g, emb, pbest, pidx, vidx,
                                    out + idx_off, lacc, ticket, out, loss_off);

  // ---- decoder ----
  p.inH = e1g; p.inL = nullptr; p.bias = db0;
  p.outH = d1h; p.outL = nullptr; p.vidx = vidx;
  p.Ci = 256; p.lg2Ci = 8; p.Ti = 64; p.Co = 256; p.To = 128;
  p.lg2U = 6; p.Umask = 63;
  p.wH = wst + W_D0A; p.wL = nullptr;
  p.K2 = 256; conv_mfma<1, 0, true, true, 1><<<dim3(256, 4), 256, 0, stream>>>(p);
  p.wH = wst + W_D0B;
  p.K2 = 512; conv_mfma<1, 1, true, true, 1><<<dim3(256, 4), 256, 0, stream>>>(p);

  CPD d; d.zpad = zpad;
  d.inH = d1h; d.wS = wst + W_DC1; d.bias = db1; d.outF = nullptr; d.outH = d2h;
  d.Ci = 256; d.Ti = 128; d.Co = 128; d.To = 256; d.lg2U = 7; d.Umask = 127;
  conv_dec<true, false><<<dim3(512, 2), 256, 0, stream>>>(d);

  d.inH = d2h; d.wS = wst + W_DC2; d.bias = db2; d.outH = d3h;
  d.Ci = 128; d.Ti = 256; d.Co = 64; d.To = 512; d.lg2U = 8; d.Umask = 255;
  conv_dec<true, false><<<dim3(1024, 1), 256, 0, stream>>>(d);

  d.inH = d3h; d.wS = wst + W_DC3; d.bias = db3; d.outF = out; d.outH = nullptr;
  d.Ci = 64; d.Ti = 512; d.Co = 32; d.To = 1024; d.lg2U = 9; d.Umask = 511;
  conv_dec<false, true><<<dim3(2048, 1), 256, 0, stream>>>(d);
}

// Round 12
// 498.230 us; speedup vs baseline: 1.1071x; 1.1071x over previous
//
#include <hip/hip_runtime.h>

// ---------------------------------------------------------------------------
// VQ-VAE forward. R20 = R18 verbatim (best measured: 503us).
//  - R19 post-mortem: setprio removal cost vq 207->219 (setprio is +5% in
//    this 2-blocks/CU DMA-overlap structure — contra the GEMM-null prior);
//    vq_post fusion cost ~36us (serialized device-scope ticket atomics +
//    threadfence x4096 blocks >> the 2 launch gaps saved). Both reverted.
//  - Final structure: fragment-linear LDS + global_load_lds DMA staging in
//    all conv kernels (no ds_write, no staging VALU), staged/pre-split
//    weights (w_prep) and x (x_prep), 64-row conv tiles at 4 blocks/CU,
//    vq_mfma = R14 schedule with setprio (pinned z, dbuf e-staging, XCD seg).
//  - Session: 746.7 -> 503 us (-33%).
// ---------------------------------------------------------------------------

typedef _Float16 half8 __attribute__((ext_vector_type(8)));
typedef _Float16 half4v __attribute__((ext_vector_type(4)));
typedef float f32x4 __attribute__((ext_vector_type(4)));
typedef float f32x16 __attribute__((ext_vector_type(16)));

#define GL_LDS(src, dst) \
  __builtin_amdgcn_global_load_lds((const __attribute__((address_space(1))) void*)(src), \
                                   (__attribute__((address_space(3))) void*)(dst), 16, 0, 0)

struct CP2 {
  const _Float16* inH; const _Float16* inL;
  const _Float16* wH; const _Float16* wL;
  const float* bias; const _Float16* zpad;
  float* outF; _Float16* outH; _Float16* outL;
  const int* vidx;
  int Ci, lg2Ci, Ti, Co, To, K2, stride, pad, lg2U, Umask;
};

template<int SP, int PAR, bool GATHER, bool RELU, int OM>
__global__ __launch_bounds__(256, 4) void conv_mfma(CP2 p) {
  __shared__ _Float16 As[2][SP * 2048];
  __shared__ _Float16 Bs[2][SP * 2048];
  const int tid = threadIdx.x;
  const int w = tid >> 6;
  const int lane = tid & 63;
  const int m = lane & 15, q = lane >> 4;
  const int btbase = blockIdx.x * 64;
  const int cobase = blockIdx.y * 64;
  const int bt = btbase + w * 16 + m;          // this lane's row (stage & MFMA)
  const int b = bt >> p.lg2U, u = bt & p.Umask;
  const int nkb = p.K2 >> 5;
  const int lw = w * 512;                      // wave-uniform LDS offset (halfs)

  int er0 = 0, er1 = 0;                        // gather codes (dt = tap only)
  if (GATHER) {
    er0 = p.vidx[b * p.Ti + u];                // tin = u (tap 0)
    if (PAR == 1) er1 = (u + 1 < p.Ti) ? p.vidx[b * p.Ti + u + 1] : 0;
  }

  auto stage = [&](int kb, int buf) {
    const int k0 = kb << 5;
    const int tap = k0 >> p.lg2Ci;
    const int ci0 = k0 & (p.Ci - 1);
    int dt;
    if (PAR == 0)      dt = 0;
    else if (PAR == 1) dt = tap;
    else               dt = tap - p.pad;
    const int tin = (PAR < 0) ? u * p.stride + dt : u + dt;
    const bool ok = (tin >= 0) && (tin < p.Ti);
    int ai;
    if (GATHER) {
      const int er = (PAR == 1 && tap == 1) ? er1 : er0;
      ai = er * 256 + ci0 + q * 8;
    } else {
      ai = (b * p.Ti + tin) * p.Ci + ci0 + q * 8;
    }
    GL_LDS(ok ? &p.inH[ai] : p.zpad, &As[buf][lw]);
    if (SP == 2) GL_LDS(ok ? &p.inL[ai] : p.zpad, &As[buf][2048 + lw]);
    const int wb = (blockIdx.y * nkb + kb) * 2048 + lw + lane * 8;
    GL_LDS(&p.wH[wb], &Bs[buf][lw]);
    if (SP == 2) GL_LDS(&p.wL[wb], &Bs[buf][2048 + lw]);
  };

  f32x4 acc[4];
#pragma unroll
  for (int j = 0; j < 4; ++j) acc[j] = {0.f, 0.f, 0.f, 0.f};

  stage(0, 0);
  for (int kb = 0; kb < nkb; ++kb) {
    const int buf = kb & 1;
    __syncthreads();                           // drains stage(kb); WAR-safe
    if (kb + 1 < nkb) stage(kb + 1, buf ^ 1);  // in flight across MFMA
    const half8 a1 = *(const half8*)&As[buf][lw + lane * 8];
    half8 a2;
    if (SP == 2) a2 = *(const half8*)&As[buf][2048 + lw + lane * 8];
#pragma unroll
    for (int ct = 0; ct < 4; ++ct) {
      const half8 b1 = *(const half8*)&Bs[buf][ct * 512 + lane * 8];
      half8 b2;
      if (SP == 2) b2 = *(const half8*)&Bs[buf][2048 + ct * 512 + lane * 8];
      acc[ct] = __builtin_amdgcn_mfma_f32_16x16x32_f16(a1, b1, acc[ct], 0, 0, 0);
      if (SP == 2) {
        acc[ct] = __builtin_amdgcn_mfma_f32_16x16x32_f16(a2, b1, acc[ct], 0, 0, 0);
        acc[ct] = __builtin_amdgcn_mfma_f32_16x16x32_f16(a1, b2, acc[ct], 0, 0, 0);
      }
    }
  }
#pragma unroll
  for (int ct = 0; ct < 4; ++ct) {
    const int co = cobase + ct * 16 + m;
    if (co < p.Co) {
      const float bv = p.bias[co];
#pragma unroll
      for (int j = 0; j < 4; ++j) {
        const int row = btbase + w * 16 + q * 4 + j;
        const int bb = row >> p.lg2U, uu = row & p.Umask;
        float v = acc[ct][j] + bv;
        if (RELU) v = fmaxf(v, 0.f);
        const int t = (PAR < 0) ? uu : 2 * uu + PAR;
        const int oi = (bb * p.To + t) * p.Co + co;
        if (OM == 3) {
          p.outF[oi] = v;
        } else if (OM == 1) {
          p.outH[oi] = (_Float16)v;
        } else {
          const _Float16 h = (_Float16)v;
          const _Float16 l = (_Float16)(v - (float)h);
          p.outH[oi] = h; p.outL[oi] = l;
        }
      }
    }
  }
}

struct CPD {
  const _Float16* inH; const _Float16* wS; const float* bias;
  const _Float16* zpad;
  float* outF; _Float16* outH;
  int Ci, Ti, Co, To, lg2U, Umask;
};

template<bool RELU, bool F32OUT>
__global__ __launch_bounds__(256, 4) void conv_dec(CPD p) {
  __shared__ _Float16 As[2][2560];             // rows 0-63 + rows 64-79 extra
  __shared__ _Float16 Bs[2][6144];             // 3 taps, fragment-linear
  const int tid = threadIdx.x;
  const int w = tid >> 6;
  const int lane = tid & 63;
  const int m = lane & 15, q = lane >> 4;
  const int btbase = blockIdx.x * 64;
  const int cobase = blockIdx.y * 64;
  const int b0 = btbase >> p.lg2U;
  const int u0 = btbase & p.Umask;
  const int nkb = p.Ci >> 5;
  const int lw = w * 512;

  auto stage = [&](int kb, int buf) {
    const int ci0 = kb << 5;
    {
      const int ur = u0 + w * 16 + m;
      const bool ok = ur < p.Ti;
      GL_LDS(ok ? &p.inH[(b0 * p.Ti + ur) * p.Ci + ci0 + q * 8] : p.zpad,
             &As[buf][lw]);
    }
    if (w == 0) {                              // rows 64-79 (only row 64 used)
      const int ur = u0 + 64 + m;
      const bool ok = ur < p.Ti;
      GL_LDS(ok ? &p.inH[(b0 * p.Ti + ur) * p.Ci + ci0 + q * 8] : p.zpad,
             &As[buf][2048]);
    }
    const int wb = (blockIdx.y * nkb + kb) * 6144;
#pragma unroll
    for (int tap = 0; tap < 3; ++tap)
      GL_LDS(&p.wS[wb + tap * 2048 + lw + lane * 8], &Bs[buf][tap * 2048 + lw]);
  };

  f32x4 aE[4], aO[4];
#pragma unroll
  for (int j = 0; j < 4; ++j) { aE[j] = {0.f,0.f,0.f,0.f}; aO[j] = {0.f,0.f,0.f,0.f}; }

  stage(0, 0);
  for (int kb = 0; kb < nkb; ++kb) {
    const int buf = kb & 1;
    __syncthreads();
    if (kb + 1 < nkb) stage(kb + 1, buf ^ 1);
    const int row = w * 16 + m;
    const half8 a0 = *(const half8*)&As[buf][lw + lane * 8];
    const int r1 = row + 1;
    const int s1 = (r1 >> 4) * 512 + ((r1 & 15) + (q << 4)) * 8;
    const half8 a1s = *(const half8*)&As[buf][s1];
#pragma unroll
    for (int ct = 0; ct < 4; ++ct) {
      const half8 w0 = *(const half8*)&Bs[buf][ct * 512 + lane * 8];
      const half8 w1 = *(const half8*)&Bs[buf][2048 + ct * 512 + lane * 8];
      const half8 w2 = *(const half8*)&Bs[buf][4096 + ct * 512 + lane * 8];
      aE[ct] = __builtin_amdgcn_mfma_f32_16x16x32_f16(a0,  w1, aE[ct], 0, 0, 0);
      aO[ct] = __builtin_amdgcn_mfma_f32_16x16x32_f16(a0,  w0, aO[ct], 0, 0, 0);
      aO[ct] = __builtin_amdgcn_mfma_f32_16x16x32_f16(a1s, w2, aO[ct], 0, 0, 0);
    }
  }
#pragma unroll
  for (int ct = 0; ct < 4; ++ct) {
    const int co = cobase + ct * 16 + m;
    if (co < p.Co) {
      const float bv = p.bias[co];
#pragma unroll
      for (int j = 0; j < 4; ++j) {
        const int u = u0 + w * 16 + q * 4 + j;
        float vE = aE[ct][j] + bv;
        float vO = aO[ct][j] + bv;
        if (RELU) { vE = fmaxf(vE, 0.f); vO = fmaxf(vO, 0.f); }
        const int oiE = (b0 * p.To + 2 * u) * p.Co + co;
        const int oiO = oiE + p.Co;
        if (F32OUT) { p.outF[oiE] = vE; p.outF[oiO] = vO; }
        else        { p.outH[oiE] = (_Float16)vE; p.outH[oiO] = (_Float16)vO; }
      }
    }
  }
}

// ---- prep kernels -----------------------------------------------------------

__global__ __launch_bounds__(256) void x_prep(const float* __restrict__ x,
                                              _Float16* __restrict__ h,
                                              _Float16* __restrict__ l,
                                              _Float16* __restrict__ zp) {
  if (blockIdx.x == 0 && threadIdx.x < 64) {   // zero page for OOB staging
    const uint4 z = {0u, 0u, 0u, 0u};
    ((uint4*)zp)[threadIdx.x] = z;
  }
  const int i = blockIdx.x * 256 + threadIdx.x;   // 1,048,576 float4s
  const float4 v = ((const float4*)x)[i];
  half4v a, b;
  a.x = (_Float16)v.x; b.x = (_Float16)(v.x - (float)a.x);
  a.y = (_Float16)v.y; b.y = (_Float16)(v.y - (float)a.y);
  a.z = (_Float16)v.z; b.z = (_Float16)(v.z - (float)a.z);
  a.w = (_Float16)v.w; b.w = (_Float16)(v.w - (float)a.w);
  ((half4v*)h)[i] = a;
  ((half4v*)l)[i] = b;
}

struct WPE { const float* w; int dh, dl, Ci, lg2Ci, KWO, Co, PAR, SP, nkb, base, dec; };
struct WPA { WPE e[9]; };

// one block per (conv, coblk, kb) tile: writes staged f16 tile(s) in
// FRAGMENT-LINEAR order: slot = (cc>>4)*512 + ((cc&15) + (g<<4))*8.
__global__ __launch_bounds__(256) void w_prep(WPA a, _Float16* __restrict__ wst) {
  const int b = (int)blockIdx.x;
  int i = 0;
#pragma unroll
  for (int j = 1; j < 9; ++j) if (b >= a.e[j].base) i = j;
  const WPE E = a.e[i];
  const int local = b - E.base;
  const int cb = local / E.nkb;
  const int kb = local - cb * E.nkb;
  const int tid = threadIdx.x;
  const int cc = tid >> 2, g = tid & 3;
  const int co = cb * 64 + cc;
  const bool okc = co < E.Co;
  const int k0 = kb << 5;
  const int tap0 = k0 >> E.lg2Ci;
  const int ci0 = k0 & (E.Ci - 1);
  const int slot = (cc >> 4) * 512 + ((cc & 15) + (g << 4)) * 8;
  if (!E.dec) {
    const int ko = (E.PAR == 0) ? 1 : (E.PAR == 1 ? 2 * tap0 : tap0);
    half8 hv, lv;
#pragma unroll
    for (int j = 0; j < 8; ++j) {
      const float wv = okc ? E.w[(co * E.Ci + ci0 + g * 8 + j) * E.KWO + ko] : 0.f;
      hv[j] = (_Float16)wv;
      lv[j] = (_Float16)(wv - (float)hv[j]);
    }
    const int off = (cb * E.nkb + kb) * 2048 + slot;
    *(half8*)&wst[E.dh + off] = hv;
    if (E.SP == 2) *(half8*)&wst[E.dl + off] = lv;
  } else {
#pragma unroll
    for (int tap = 0; tap < 3; ++tap) {
      half8 hv;
#pragma unroll
      for (int j = 0; j < 8; ++j) {
        const float wv = okc ? E.w[(co * E.Ci + ci0 + g * 8 + j) * 3 + tap] : 0.f;
        hv[j] = (_Float16)wv;
      }
      *(half8*)&wst[E.dh + ((cb * E.nkb + kb) * 3 + tap) * 2048 + slot] = hv;
    }
  }
}

__global__ __launch_bounds__(256) void emb_prep(const float* __restrict__ emb,
                                                _Float16* __restrict__ hi,
                                                _Float16* __restrict__ lo,
                                                float* __restrict__ nrm) {
  const int k = blockIdx.x * 4 + (threadIdx.x >> 6);
  const int lane = threadIdx.x & 63;
  const int i = k * 64 + lane;
  const float4 v = ((const float4*)emb)[i];
  half4v a, b;
  a.x = (_Float16)v.x; b.x = (_Float16)(v.x - (float)a.x);
  a.y = (_Float16)v.y; b.y = (_Float16)(v.y - (float)a.y);
  a.z = (_Float16)v.z; b.z = (_Float16)(v.z - (float)a.z);
  a.w = (_Float16)v.w; b.w = (_Float16)(v.w - (float)a.w);
  ((half4v*)hi)[i] = a;
  ((half4v*)lo)[i] = b;
  double s = (double)v.x * v.x + (double)v.y * v.y +
             (double)v.z * v.z + (double)v.w * v.w;
  for (int off = 32; off; off >>= 1) s += __shfl_down(s, off);
  if (lane == 0) nrm[k] = (float)s;
}

// VQ argmin, R14 form verbatim (best measured ~207-210us; setprio RESTORED
// — R19 A/B: removing it cost 12us / MfmaUtil 48->43 in this structure).
__global__ __launch_bounds__(256, 2) void vq_mfma(const _Float16* __restrict__ z1g,
                                                  const _Float16* __restrict__ z2g,
                                                  const _Float16* __restrict__ e1g,
                                                  const _Float16* __restrict__ e2g,
                                                  const float* __restrict__ nrm,
                                                  float* __restrict__ pbest,
                                                  int* __restrict__ pidx) {
  __shared__ _Float16 es[2 * 2 * 4096];   // [buf][arr][4096 halfs] = 32 KB
  const int tid = threadIdx.x;
  const int lane = tid & 63;
  const int w = tid >> 6;
  const int m32 = lane & 31;
  const int hi = lane >> 5;
  const int seg = blockIdx.x & 7, rb = blockIdx.x >> 3;   // XCD = bid%8 = seg
  const int rbase = rb * 128;
  const int row_g = rbase + w * 32 + m32;

  half8 za[16], zb[16];
#pragma unroll
  for (int c = 0; c < 16; ++c) {
    const int zi = row_g * 256 + c * 16 + hi * 8;
    za[c] = *(const half8*)&z1g[zi];
    zb[c] = *(const half8*)&z2g[zi];
  }

  float best[16]; int bk[16];
#pragma unroll
  for (int i = 0; i < 16; ++i) { best[i] = 3.4e38f; bk[i] = 0; }

  const int sbase = (seg * 1024 + ((tid >> 7) & 1) * 32 + (tid & 31)) * 256
                  + ((tid >> 6) & 1) * 16 + ((tid >> 5) & 1) * 8;
  const int lw = w * 512;                 // wave-uniform LDS dst (halfs)

  auto stage = [&](int cc_, int kb_, int buf_) {
    const int off = sbase + cc_ * 32768 + kb_ * 32;
    __builtin_amdgcn_global_load_lds(
        (const __attribute__((address_space(1))) void*)(e1g + off),
        (__attribute__((address_space(3))) void*)&es[(buf_ * 2 + 0) * 4096 + lw], 16, 0, 0);
    __builtin_amdgcn_global_load_lds(
        (const __attribute__((address_space(1))) void*)(e1g + off + 16384),
        (__attribute__((address_space(3))) void*)&es[(buf_ * 2 + 0) * 4096 + 2048 + lw], 16, 0, 0);
    __builtin_amdgcn_global_load_lds(
        (const __attribute__((address_space(1))) void*)(e2g + off),
        (__attribute__((address_space(3))) void*)&es[(buf_ * 2 + 1) * 4096 + lw], 16, 0, 0);
    __builtin_amdgcn_global_load_lds(
        (const __attribute__((address_space(1))) void*)(e2g + off + 16384),
        (__attribute__((address_space(3))) void*)&es[(buf_ * 2 + 1) * 4096 + 2048 + lw], 16, 0, 0);
  };

  stage(0, 0, 0);                         // prologue: step (cc=0,kb=0) -> buf0

  const int lb = lane * 8;                // read base (halfs)
  f32x16 acc[4];
  for (int cc = 0; cc < 8; ++cc) {
    const int cbase = seg * 1024 + cc * 128;
#pragma unroll
    for (int ct = 0; ct < 4; ++ct) {
#pragma unroll
      for (int rg = 0; rg < 16; ++rg) acc[ct][rg] = 0.f;
    }
#pragma unroll
    for (int kb = 0; kb < 8; ++kb) {
      const int buf = kb & 1;
      const _Float16* e1s = &es[(buf * 2 + 0) * 4096];
      const _Float16* e2s = &es[(buf * 2 + 1) * 4096];
      __syncthreads();
      if (kb < 7)      stage(cc, kb + 1, buf ^ 1);
      else if (cc < 7) stage(cc + 1, 0, buf ^ 1);
      __builtin_amdgcn_s_setprio(1);
#pragma unroll
      for (int ct = 0; ct < 4; ++ct) {
#pragma unroll
        for (int k16 = 0; k16 < 2; ++k16) {
          const half8 b1 = *(const half8*)&e1s[ct * 1024 + k16 * 512 + lb];
          const half8 b2 = *(const half8*)&e2s[ct * 1024 + k16 * 512 + lb];
          const half8 a1 = za[kb * 2 + k16];
          const half8 a2 = zb[kb * 2 + k16];
          acc[ct] = __builtin_amdgcn_mfma_f32_32x32x16_f16(a1, b1, acc[ct], 0, 0, 0);
          acc[ct] = __builtin_amdgcn_mfma_f32_32x32x16_f16(a2, b1, acc[ct], 0, 0, 0);
          acc[ct] = __builtin_amdgcn_mfma_f32_32x32x16_f16(a1, b2, acc[ct], 0, 0, 0);
        }
      }
      __builtin_amdgcn_s_setprio(0);
    }
#pragma unroll
    for (int ct = 0; ct < 4; ++ct) {
      const int k = cbase + ct * 32 + m32;
      const float nv = nrm[k];
#pragma unroll
      for (int rg = 0; rg < 16; ++rg) {
        const float d = nv - 2.f * acc[ct][rg];
        if (d < best[rg]) { best[rg] = d; bk[rg] = k; }
      }
    }
  }
#pragma unroll
  for (int rg = 0; rg < 16; ++rg) {
    float bv = best[rg]; int kv = bk[rg];
    for (int off = 1; off < 32; off <<= 1) {
      const float ob = __shfl_xor(bv, off);
      const int ok = __shfl_xor(kv, off);
      if (ob < bv || (ob == bv && ok < kv)) { bv = ob; kv = ok; }
    }
    if (m32 == 0) {
      const int row = rbase + w * 32 + (rg & 3) + 8 * (rg >> 2) + 4 * hi;
      pbest[seg * 16384 + row] = bv;
      pidx[seg * 16384 + row] = kv;
    }
  }
}

__global__ void merge_kernel(const float* __restrict__ pbest, const int* __restrict__ pidx,
                             int* __restrict__ vidx, float* __restrict__ out_idx,
                             float* __restrict__ lacc) {
  const int n = blockIdx.x * 256 + threadIdx.x;
  float bv = pbest[n]; int kv = pidx[n];
#pragma unroll
  for (int s = 1; s < 8; ++s) {
    const float ob = pbest[s * 16384 + n];
    const int ok = pidx[s * 16384 + n];
    if (ob < bv || (ob == bv && ok < kv)) { bv = ob; kv = ok; }
  }
  vidx[n] = kv;
  out_idx[n] = (float)kv;
  if (n == 0) *lacc = 0.f;
}

__global__ __launch_bounds__(256) void loss_kernel(const _Float16* __restrict__ z1g,
                                                   const _Float16* __restrict__ z2g,
                                                   const float* __restrict__ emb,
                                                   const int* __restrict__ vidx,
                                                   float* __restrict__ lacc) {
  const int g4 = blockIdx.x * 256 + threadIdx.x;
  const int e0 = g4 * 4;
  const int n = e0 >> 8, c = e0 & 255;
  const half4v a = ((const half4v*)z1g)[g4];
  const half4v b = ((const half4v*)z2g)[g4];
  const float4 q4 = *(const float4*)&emb[vidx[n] * 256 + c];
  const float dx = ((float)a.x + (float)b.x) - q4.x;
  const float dy = ((float)a.y + (float)b.y) - q4.y;
  const float dz = ((float)a.z + (float)b.z) - q4.z;
  const float dw = ((float)a.w + (float)b.w) - q4.w;
  float s = dx * dx + dy * dy + dz * dz + dw * dw;
  for (int off = 32; off; off >>= 1) s += __shfl_down(s, off);
  __shared__ float red[4];
  if ((threadIdx.x & 63) == 0) red[threadIdx.x >> 6] = s;
  __syncthreads();
  if (threadIdx.x == 0) atomicAdd(lacc, red[0] + red[1] + red[2] + red[3]);
}

__global__ void fin_kernel(const float* __restrict__ lacc, float* __restrict__ out, int loff) {
  if (threadIdx.x == 0) {
    const float l = *lacc * (1.f / 4194304.f);
    out[loff] = l;
    out[loff + 1] = l;
  }
}

extern "C" void kernel_launch(void* const* d_in, const int* in_sizes, int n_in,
                              void* d_out, int out_size, void* d_ws, size_t ws_size,
                              hipStream_t stream) {
  const float* x   = (const float*)d_in[0];
  const float* ew0 = (const float*)d_in[1];  const float* eb0 = (const float*)d_in[2];
  const float* ew1 = (const float*)d_in[3];  const float* eb1 = (const float*)d_in[4];
  const float* ew2 = (const float*)d_in[5];  const float* eb2 = (const float*)d_in[6];
  const float* pw  = (const float*)d_in[7];  const float* pb  = (const float*)d_in[8];
  const float* emb = (const float*)d_in[9];
  const float* dw0 = (const float*)d_in[10]; const float* db0 = (const float*)d_in[11];
  const float* dw1 = (const float*)d_in[12]; const float* db1 = (const float*)d_in[13];
  const float* dw2 = (const float*)d_in[14]; const float* db2 = (const float*)d_in[15];
  const float* dw3 = (const float*)d_in[16]; const float* db3 = (const float*)d_in[17];
  float* ws  = (float*)d_ws;
  float* out = (float*)d_out;

  const int A0 = 0, B0 = 4194304, C0 = 8388608, TL = 12582912;
  _Float16* h0h = (_Float16*)(ws + C0);            // x split (enc0 input)
  _Float16* h0l = h0h + 4194304;
  _Float16* h1h = (_Float16*)(ws + B0);
  _Float16* h1l = h1h + 4194304;
  _Float16* h2h = (_Float16*)(ws + A0);
  _Float16* h2l = h2h + 4194304;
  _Float16* h3h = (_Float16*)(ws + B0);
  _Float16* h3l = h3h + 4194304;
  _Float16* z1g = (_Float16*)(ws + A0);
  _Float16* z2g = z1g + 4194304;
  _Float16* e1g = (_Float16*)(ws + B0);
  _Float16* e2g = e1g + 2097152;
  float* pbest = ws + B0 + 2097152;
  int*   pidx  = (int*)(ws + B0 + 2097152 + 131072);
  _Float16* d1h = (_Float16*)(ws + C0);
  _Float16* d2h = (_Float16*)(ws + A0);
  _Float16* d3h = (_Float16*)(ws + B0);
  float* nrm  = ws + TL;
  int*   vidx = (int*)(ws + TL + 8192);
  float* lacc = ws + TL + 8192 + 16384;
  _Float16* zpad = (_Float16*)(ws + TL + 26624);   // 1KB zero page
  _Float16* wst = (_Float16*)(ws + TL + 32768);    // staged weights (~1.44MB)

  // staged-weight offsets (halfs)
  const int W_E0H = 0,      W_E0L = 6144;
  const int W_E1H = 12288,  W_E1L = 36864;
  const int W_E2H = 61440,  W_E2L = 159744;
  const int W_PJH = 258048, W_PJL = 323584;
  const int W_D0A = 389120, W_D0B = 454656;
  const int W_DC1 = 585728, W_DC2 = 684032, W_DC3 = 708608;

  const int idx_off  = out_size - 16384;
  const int loss_off = out_size - 16386;

  // ---- prep: x split + zero page + all weights staged (2 dispatches) ----
  x_prep<<<4096, 256, 0, stream>>>(x, h0h, h0l, zpad);
  WPA wa;
  wa.e[0] = {ew0, W_E0H, W_E0L, 32,  5, 3, 64,  -1, 2, 3,  0,   0};
  wa.e[1] = {ew1, W_E1H, W_E1L, 64,  6, 3, 128, -1, 2, 6,  3,   0};
  wa.e[2] = {ew2, W_E2H, W_E2L, 128, 7, 3, 256, -1, 2, 12, 15,  0};
  wa.e[3] = {pw,  W_PJH, W_PJL, 256, 8, 1, 256, -1, 2, 8,  63,  0};
  wa.e[4] = {dw0, W_D0A, 0,     256, 8, 3, 256,  0, 1, 8,  95,  0};
  wa.e[5] = {dw0, W_D0B, 0,     256, 8, 3, 256,  1, 1, 16, 127, 0};
  wa.e[6] = {dw1, W_DC1, 0,     256, 8, 3, 128, -1, 1, 8,  191, 1};
  wa.e[7] = {dw2, W_DC2, 0,     128, 7, 3, 64,  -1, 1, 4,  207, 1};
  wa.e[8] = {dw3, W_DC3, 0,     64,  6, 3, 32,  -1, 1, 2,  211, 1};
  w_prep<<<213, 256, 0, stream>>>(wa, wst);

  CP2 p; p.vidx = nullptr; p.inH = nullptr; p.inL = nullptr;
  p.outF = nullptr; p.outH = nullptr; p.outL = nullptr; p.zpad = zpad;

  // ---- encoder (3-pass f16 split MFMA; DMA staging; 64-row tiles) ----
  p.inH = h0h; p.inL = h0l; p.wH = wst + W_E0H; p.wL = wst + W_E0L;
  p.bias = eb0; p.outH = h1h; p.outL = h1l;
  p.Ci = 32; p.lg2Ci = 5; p.Ti = 512; p.Co = 64; p.To = 256;
  p.K2 = 96; p.stride = 2; p.pad = 1; p.lg2U = 8; p.Umask = 255;
  conv_mfma<2, -1, false, true, 0><<<dim3(1024, 1), 256, 0, stream>>>(p);

  p.inH = h1h; p.inL = h1l; p.wH = wst + W_E1H; p.wL = wst + W_E1L;
  p.bias = eb1; p.outH = h2h; p.outL = h2l;
  p.Ci = 64; p.lg2Ci = 6; p.Ti = 256; p.Co = 128; p.To = 128; p.K2 = 192;
  p.lg2U = 7; p.Umask = 127;
  conv_mfma<2, -1, false, true, 0><<<dim3(512, 2), 256, 0, stream>>>(p);

  p.inH = h2h; p.inL = h2l; p.wH = wst + W_E2H; p.wL = wst + W_E2L;
  p.bias = eb2; p.outH = h3h; p.outL = h3l;
  p.Ci = 128; p.lg2Ci = 7; p.Ti = 128; p.Co = 256; p.To = 64; p.K2 = 384;
  p.lg2U = 6; p.Umask = 63;
  conv_mfma<2, -1, false, true, 0><<<dim3(256, 4), 256, 0, stream>>>(p);

  p.inH = h3h; p.inL = h3l; p.wH = wst + W_PJH; p.wL = wst + W_PJL;
  p.bias = pb; p.outH = z1g; p.outL = z2g;
  p.Ci = 256; p.lg2Ci = 8; p.Ti = 64; p.Co = 256; p.To = 64;
  p.K2 = 256; p.stride = 1; p.pad = 0; p.lg2U = 6; p.Umask = 63;
  conv_mfma<2, -1, false, false, 0><<<dim3(256, 4), 256, 0, stream>>>(p);

  // ---- VQ ----
  emb_prep<<<2048, 256, 0, stream>>>(emb, e1g, e2g, nrm);
  vq_mfma<<<1024, 256, 0, stream>>>(z1g, z2g, e1g, e2g, nrm, pbest, pidx);
  merge_kernel<<<64, 256, 0, stream>>>(pbest, pidx, vidx, out + idx_off, lacc);
  loss_kernel<<<4096, 256, 0, stream>>>(z1g, z2g, emb, vidx, lacc);
  fin_kernel<<<1, 64, 0, stream>>>(lacc, out, loss_off);

  // ---- decoder ----
  p.inH = e1g; p.inL = nullptr; p.bias = db0;
  p.outH = d1h; p.outL = nullptr; p.vidx = vidx;
  p.Ci = 256; p.lg2Ci = 8; p.Ti = 64; p.Co = 256; p.To = 128;
  p.lg2U = 6; p.Umask = 63;
  p.wH = wst + W_D0A; p.wL = nullptr;
  p.K2 = 256; conv_mfma<1, 0, true, true, 1><<<dim3(256, 4), 256, 0, stream>>>(p);
  p.wH = wst + W_D0B;
  p.K2 = 512; conv_mfma<1, 1, true, true, 1><<<dim3(256, 4), 256, 0, stream>>>(p);

  CPD d; d.zpad = zpad;
  d.inH = d1h; d.wS = wst + W_DC1; d.bias = db1; d.outF = nullptr; d.outH = d2h;
  d.Ci = 256; d.Ti = 128; d.Co = 128; d.To = 256; d.lg2U = 7; d.Umask = 127;
  conv_dec<true, false><<<dim3(512, 2), 256, 0, stream>>>(d);

  d.inH = d2h; d.wS = wst + W_DC2; d.bias = db2; d.outH = d3h;
  d.Ci = 128; d.Ti = 256; d.Co = 64; d.To = 512; d.lg2U = 8; d.Umask = 255;
  conv_dec<true, false><<<dim3(1024, 1), 256, 0, stream>>>(d);

  d.inH = d3h; d.wS = wst + W_DC3; d.bias = db3; d.outF = out; d.outH = nullptr;
  d.Ci = 64; d.Ti = 512; d.Co = 32; d.To = 1024; d.lg2U = 9; d.Umask = 511;
  conv_dec<false, true><<<dim3(2048, 1), 256, 0, stream>>>(d);
}